// Round 3
// baseline (1057.353 us; speedup 1.0000x reference)
//
#include <hip/hip_runtime.h>

typedef _Float16 f16;
typedef _Float16 f16x4 __attribute__((ext_vector_type(4)));
typedef _Float16 f16x8 __attribute__((ext_vector_type(8)));
typedef float f32x4 __attribute__((ext_vector_type(4)));
typedef unsigned long long u64;

// dims
#define BB 128
#define TT 128
#define IIN 512
#define HHID 512
#define EEX 256

// ---------------- prep: fp32 -> fp16 conversions + tag-region zeroing ----------------
__global__ void prep_kernel(const float* __restrict__ x,
    const float* __restrict__ W_ir, const float* __restrict__ W_iz, const float* __restrict__ W_in,
    const float* __restrict__ W_hr, const float* __restrict__ W_hz, const float* __restrict__ W_hn,
    f16* __restrict__ xb, f16* __restrict__ WiCat, f16* __restrict__ WhCat,
    u64* __restrict__ hglob)
{
  size_t idx = (size_t)blockIdx.x * 256 + threadIdx.x;

  const size_t NX = (size_t)TT * BB * (IIN / 8);         // 1,048,576 chunks of 8
  const size_t NW = (size_t)2 * 1536 * (512 / 8);        // 196,608 per weight set
  if (idx < NX) {
    int t = (int)(idx / (BB * 64));
    int rem = (int)(idx % (BB * 64));
    int b = rem >> 6;
    int k0 = (rem & 63) * 8;
    const float* src = x + ((size_t)b * TT + t) * IIN + k0;
    f16x8 v;
#pragma unroll
    for (int j = 0; j < 8; ++j) v[j] = (f16)src[j];
    *(f16x8*)(xb + ((size_t)t * BB + b) * IIN + k0) = v;
  } else if (idx < NX + 2 * NW) {
    size_t w = idx - NX;
    bool isI = w < NW;
    size_t w2 = isI ? w : w - NW;
    int l = (int)(w2 / (1536 * 64));
    int rem = (int)(w2 % (1536 * 64));
    int n = rem >> 6;
    int k0 = (rem & 63) * 8;
    int g = n >> 9, j = n & 511;
    const float* W = isI ? (g == 0 ? W_ir : (g == 1 ? W_iz : W_in))
                         : (g == 0 ? W_hr : (g == 1 ? W_hz : W_hn));
    const float* src = W + ((size_t)l * 512 + j) * 512 + k0;
    f16x8 v;
#pragma unroll
    for (int jj = 0; jj < 8; ++jj) v[jj] = (f16)src[jj];
    f16* dst = isI ? WiCat : WhCat;
    *(f16x8*)(dst + ((size_t)l * 1536 + n) * 512 + k0) = v;
  } else if (idx < NX + 2 * NW + 131072) {
    // zero both layers' tagged exchange buffers (2 layers * 2 bufs * 128 rows * 256 u64)
    size_t z = idx - (NX + 2 * NW);
    __hip_atomic_store(hglob + z, (u64)0, __ATOMIC_RELAXED, __HIP_MEMORY_SCOPE_AGENT);
  }
}

// ---------------- er[l][b][h] = sum_e extra[b][e] * W_er[l][h][e] (f32) ----------------
__global__ void er_kernel(const float* __restrict__ extra, const float* __restrict__ W_er,
                          float* __restrict__ er)
{
  int idx = blockIdx.x * 256 + threadIdx.x;   // 2*128*512 = 131072
  int l = idx >> 16;
  int b = (idx >> 9) & 127;
  int h = idx & 511;
  const float* e = extra + (size_t)b * EEX;
  const float* w = W_er + ((size_t)l * 512 + h) * EEX;
  float acc = 0.f;
#pragma unroll 4
  for (int k = 0; k < EEX; k += 4)
    acc += e[k] * w[k] + e[k + 1] * w[k + 1] + e[k + 2] * w[k + 2] + e[k + 3] * w[k + 3];
  er[idx] = acc;
}

// ---------------- input-projection GEMM: Gi[m][n] = A[m,:] . Wcat[n,:] + bias + er ----------------
// M=16384 (m = t*128+b), N=1536, K=512. A,Wcat row-major fp16 (K contiguous). Output fp16.
__global__ __launch_bounds__(256, 2) void gemm_gi(
    const f16* __restrict__ A, const f16* __restrict__ Wcat,
    const float* __restrict__ b_r, const float* __restrict__ b_z, const float* __restrict__ b_n,
    const float* __restrict__ er,    // [128][512] this layer
    f16* __restrict__ Gi)            // [16384][1536]
{
  const int tid = threadIdx.x;
  const int wave = tid >> 6, lane = tid & 63;
  const int bm = blockIdx.x % 128, bn = blockIdx.x / 128;  // 128 x 12 tiles
  const int m0 = bm * 128, n0 = bn * 128;
  const int wm = wave >> 1, wn = wave & 1;
  const int r16 = lane & 15, khi = lane >> 4;

  __shared__ f16 As[128 * 40];   // padded stride 40 f16
  __shared__ f16 Bs[128 * 40];

  const f32x4 vzero = {0.f, 0.f, 0.f, 0.f};
  f32x4 acc[4][4];
#pragma unroll
  for (int mi = 0; mi < 4; ++mi)
#pragma unroll
    for (int ni = 0; ni < 4; ++ni) acc[mi][ni] = vzero;

  const int srow = tid >> 1, skoff = (tid & 1) * 16;
  const f16* Aptr = A + (size_t)(m0 + srow) * 512 + skoff;
  const f16* Bptr = Wcat + (size_t)(n0 + srow) * 512 + skoff;

  for (int ks = 0; ks < 512; ks += 32) {
    f16x8 a0 = *(const f16x8*)(Aptr + ks);
    f16x8 a1 = *(const f16x8*)(Aptr + ks + 8);
    f16x8 b0 = *(const f16x8*)(Bptr + ks);
    f16x8 b1 = *(const f16x8*)(Bptr + ks + 8);
    *(f16x8*)(As + srow * 40 + skoff)     = a0;
    *(f16x8*)(As + srow * 40 + skoff + 8) = a1;
    *(f16x8*)(Bs + srow * 40 + skoff)     = b0;
    *(f16x8*)(Bs + srow * 40 + skoff + 8) = b1;
    __syncthreads();
    f16x8 af[4], bf[4];
#pragma unroll
    for (int mi = 0; mi < 4; ++mi)
      af[mi] = *(const f16x8*)(As + (wm * 64 + mi * 16 + r16) * 40 + khi * 8);
#pragma unroll
    for (int ni = 0; ni < 4; ++ni)
      bf[ni] = *(const f16x8*)(Bs + (wn * 64 + ni * 16 + r16) * 40 + khi * 8);
#pragma unroll
    for (int mi = 0; mi < 4; ++mi)
#pragma unroll
      for (int ni = 0; ni < 4; ++ni)
        acc[mi][ni] = __builtin_amdgcn_mfma_f32_16x16x32_f16(af[mi], bf[ni], acc[mi][ni], 0, 0, 0);
    __syncthreads();
  }

  // epilogue: C/D layout col = lane&15, row = (lane>>4)*4 + v  [m89 verified]
#pragma unroll
  for (int mi = 0; mi < 4; ++mi) {
#pragma unroll
    for (int v = 0; v < 4; ++v) {
      int gm = m0 + wm * 64 + mi * 16 + khi * 4 + v;
      int b = gm & 127;
#pragma unroll
      for (int ni = 0; ni < 4; ++ni) {
        int gn = n0 + wn * 64 + ni * 16 + r16;
        int j = gn & 511;
        float bias, add = 0.f;
        if (gn < 512)       { bias = b_r[j]; add = er[(size_t)b * 512 + j]; }
        else if (gn < 1024) { bias = b_z[j]; }
        else                { bias = b_n[j]; }
        float val = acc[mi][ni][v] + bias + add;
        Gi[(size_t)gm * 1536 + gn] = (f16)val;
      }
    }
  }
}

// ---------------- recurrence: 8 clusters (16 rows) x 8 col-slice blocks (64 hid cols) ----------------
// Cross-block exchange via SELF-VALIDATING TAGGED u64s at the coherence point:
//   u64 = { lo32: 2 x f16 h-values, hi32: tag = t+1 }.
// No fences, no arrival counters, no vmcnt stalls: producers fire-and-forget tagged stores;
// consumers poll their own data words until the tag matches. Double-buffered by (t+1)&1.
__global__ __launch_bounds__(384, 1) void recur_kernel(
    const f16* __restrict__ Whcat,   // [1536][512] this layer
    const f16* __restrict__ Gi,      // [16384][1536] fp16
    f16* __restrict__ h0seq,         // layer0: [T*128][512] out (else null)
    float* __restrict__ outs,        // layer1: d_out [128][T][512] (else null)
    float* __restrict__ hfin,        // d_out tail + layer*128*512
    u64* __restrict__ hglob,         // this layer: [2][128][256] tagged u64
    int layer)
{
  const int tid = threadIdx.x;
  const int wave = tid >> 6, lane = tid & 63;
  const int cluster = blockIdx.x & 7;   // row group: rows cluster*16..+15
  const int s = blockIdx.x >> 3;        // col slice: hidden cols s*64..+63
  const int r16 = lane & 15, khi = lane >> 4;

  __shared__ f16 hcur[16 * 520];        // padded (520 f16/row)
  __shared__ float pre[12][16][17];     // 12 gate-col tiles, padded
  __shared__ float hf32[16 * 64];       // fp32 master h for own slice

  // ---- weights -> registers (loop-invariant B-fragments), pinned ----
  f16x8 wf0[16], wf1[16];
  {
    int tau0 = wave, tau1 = wave + 6;
    const f16* w0 = Whcat + (size_t)((tau0 >> 2) * 512 + s * 64 + (tau0 & 3) * 16 + r16) * 512 + khi * 8;
    const f16* w1 = Whcat + (size_t)((tau1 >> 2) * 512 + s * 64 + (tau1 & 3) * 16 + r16) * 512 + khi * 8;
#pragma unroll
    for (int c = 0; c < 16; ++c) {
      wf0[c] = *(const f16x8*)(w0 + c * 32);
      wf1[c] = *(const f16x8*)(w1 + c * 32);
    }
#pragma unroll
    for (int c = 0; c < 16; ++c)
      asm volatile("" : "+v"(wf0[c]), "+v"(wf1[c]));
  }

  // zero-init h state
  for (int i = tid; i < 16 * 520 / 8; i += 384) {
    f16x8 z;
#pragma unroll
    for (int j = 0; j < 8; ++j) z[j] = (f16)0.f;
    ((f16x8*)hcur)[i] = z;
  }
  for (int i = tid; i < 1024; i += 384) hf32[i] = 0.f;
  __syncthreads();

  // blend mapping: 256 active threads, each owns (row, 4 consecutive cols)
  const int brow = tid >> 4;            // 0..15 (valid when tid<256)
  const int qj = tid & 15;              // col quad: cols qj*4 .. qj*4+3
  const bool act = tid < 256;
  const int gr = cluster * 16 + brow;

  // producer store slots: 2 u64 per act thread
  u64* hdst0 = hglob + (size_t)gr * 256 + s * 32 + qj * 2;   // + nbuf*32768

  // Gi prefetch (raw f16x4, converted at use)
  f16x4 pga, pgb, pgc;
  if (act) {
    const f16* g = Gi + ((size_t)gr) * 1536 + s * 64 + qj * 4;
    pga = *(const f16x4*)g;
    pgb = *(const f16x4*)(g + 512);
    pgc = *(const f16x4*)(g + 1024);
  }

  for (int t = 0; t < TT; ++t) {
    // ---- MFMA: pre[m, gatecol] = h . Whcat^T ----
    const f32x4 vzero = {0.f, 0.f, 0.f, 0.f};
    f32x4 acc0 = vzero, acc1 = vzero;
#pragma unroll
    for (int c = 0; c < 16; ++c) {
      f16x8 a = *(const f16x8*)(hcur + r16 * 520 + c * 32 + khi * 8);
      acc0 = __builtin_amdgcn_mfma_f32_16x16x32_f16(a, wf0[c], acc0, 0, 0, 0);
      acc1 = __builtin_amdgcn_mfma_f32_16x16x32_f16(a, wf1[c], acc1, 0, 0, 0);
    }
#pragma unroll
    for (int v = 0; v < 4; ++v) {
      pre[wave][khi * 4 + v][r16] = acc0[v];
      pre[wave + 6][khi * 4 + v][r16] = acc1[v];
    }
    __syncthreads();

    // ---- blend: gates + state update; pack pairs + tag -> fire-and-forget stores ----
    if (act) {
      int nbuf = (t + 1) & 1;
      u64 tag = ((u64)(unsigned)(t + 1)) << 32;
      float hn[4];
#pragma unroll
      for (int c = 0; c < 4; ++c) {
        int j = qj * 4 + c;
        float pr = pre[j >> 4][brow][j & 15];
        float pz = pre[4 + (j >> 4)][brow][j & 15];
        float pn = pre[8 + (j >> 4)][brow][j & 15];
        float rg = 1.f / (1.f + __expf(-((float)pga[c] + pr)));
        float zg = 1.f / (1.f + __expf(-((float)pgb[c] + pz)));
        float xn = (float)pgc[c] + rg * pn;
        xn = fminf(15.f, fmaxf(-15.f, xn));
        float e2 = __expf(2.f * xn);
        float nn = (e2 - 1.f) / (e2 + 1.f);
        int li = brow * 64 + j;
        float hold = hf32[li];
        float hnew = (1.f - zg) * nn + zg * hold;
        hf32[li] = hnew;
        hn[c] = hnew;
        if (layer == 0)
          h0seq[((size_t)t * 128 + gr) * 512 + s * 64 + j] = (f16)hnew;
        else
          outs[((size_t)gr * TT + t) * 512 + s * 64 + j] = hnew;
        if (t == TT - 1)
          hfin[(size_t)gr * 512 + s * 64 + j] = hnew;
      }
      union { f16 h2[2]; unsigned u; } p0, p1;
      p0.h2[0] = (f16)hn[0]; p0.h2[1] = (f16)hn[1];
      p1.h2[0] = (f16)hn[2]; p1.h2[1] = (f16)hn[3];
      u64* d = hdst0 + (size_t)nbuf * 32768;
      __hip_atomic_store(d,     tag | p0.u, __ATOMIC_RELAXED, __HIP_MEMORY_SCOPE_AGENT);
      __hip_atomic_store(d + 1, tag | p1.u, __ATOMIC_RELAXED, __HIP_MEMORY_SCOPE_AGENT);
    }
    if (t == TT - 1) break;

    // ---- prefetch Gi[t+1] (overlaps the poll below) ----
    if (act) {
      const f16* g = Gi + ((size_t)((t + 1) * 128 + gr)) * 1536 + s * 64 + qj * 4;
      pga = *(const f16x4*)g;
      pgb = *(const f16x4*)(g + 512);
      pgc = *(const f16x4*)(g + 1024);
    }

    // ---- poll tagged exchange words for the whole cluster (16 rows x 512 cols / 2) ----
    {
      int nbuf = (t + 1) & 1;
      const unsigned wanted = (unsigned)(t + 1);
      const u64* hsrc = hglob + (size_t)nbuf * 32768 + (size_t)cluster * 16 * 256;
      u64 vv[11];
#pragma unroll
      for (int u = 0; u < 11; ++u) {
        int i = tid + u * 384;
        if (i < 4096)
          vv[u] = __hip_atomic_load(hsrc + i, __ATOMIC_RELAXED, __HIP_MEMORY_SCOPE_AGENT);
      }
      for (;;) {
        bool all = true;
#pragma unroll
        for (int u = 0; u < 11; ++u) {
          int i = tid + u * 384;
          if (i < 4096 && (unsigned)(vv[u] >> 32) != wanted) {
            all = false;
            vv[u] = __hip_atomic_load(hsrc + i, __ATOMIC_RELAXED, __HIP_MEMORY_SCOPE_AGENT);
          }
        }
        if (all) break;
      }
#pragma unroll
      for (int u = 0; u < 11; ++u) {
        int i = tid + u * 384;
        if (i < 4096) {
          int row = i >> 8, cq = i & 255;
          *(unsigned*)(hcur + row * 520 + cq * 2) = (unsigned)vv[u];
        }
      }
    }
    __syncthreads();
  }
}

// ---------------- launcher ----------------
extern "C" void kernel_launch(void* const* d_in, const int* in_sizes, int n_in,
                              void* d_out, int out_size, void* d_ws, size_t ws_size,
                              hipStream_t stream) {
  const float* x     = (const float*)d_in[0];
  const float* extra = (const float*)d_in[1];
  const float* W_ir  = (const float*)d_in[2];
  const float* b_ir  = (const float*)d_in[3];
  const float* W_hr  = (const float*)d_in[4];
  const float* W_iz  = (const float*)d_in[5];
  const float* b_iz  = (const float*)d_in[6];
  const float* W_hz  = (const float*)d_in[7];
  const float* W_in  = (const float*)d_in[8];
  const float* b_in  = (const float*)d_in[9];
  const float* W_hn  = (const float*)d_in[10];
  const float* W_er  = (const float*)d_in[11];
  float* out = (float*)d_out;

  char* ws = (char*)d_ws;
  f16* WiCat   = (f16*)(ws);                   // 2*1536*512 fp16 = 3,145,728 B
  f16* WhCat   = (f16*)(ws + 3145728);         // 3,145,728 B
  f16* xb      = (f16*)(ws + 6291456);         // 16,777,216 B
  f16* h0seq   = (f16*)(ws + 23068672);        // 16,777,216 B
  float* er    = (float*)(ws + 39845888);      // 524,288 B
  f16* Gi      = (f16*)(ws + 40370176);        // 16384*1536*2 = 50,331,648 B
  u64* hglob   = (u64*)(ws + 90701824);        // 2 layers * 2 bufs * 128 * 256 u64 = 1 MB

  prep_kernel<<<6144, 256, 0, stream>>>(x, W_ir, W_iz, W_in, W_hr, W_hz, W_hn,
                                        xb, WiCat, WhCat, hglob);
  er_kernel<<<512, 256, 0, stream>>>(extra, W_er, er);

  float* outs = out;                              // [128][128][512]
  float* hfin = out + (size_t)BB * TT * HHID;     // [2][128][512]

  for (int l = 0; l < 2; ++l) {
    gemm_gi<<<1536, 256, 0, stream>>>(
        l == 0 ? xb : h0seq,
        WiCat + (size_t)l * 1536 * 512,
        b_ir + (size_t)l * 512, b_iz + (size_t)l * 512, b_in + (size_t)l * 512,
        er + (size_t)l * 128 * 512,
        Gi);
    recur_kernel<<<64, 384, 0, stream>>>(
        WhCat + (size_t)l * 1536 * 512, Gi,
        l == 0 ? h0seq : (f16*)nullptr,
        l == 0 ? (float*)nullptr : outs,
        hfin + (size_t)l * 128 * 512,
        hglob + (size_t)l * 65536, l);
  }
}

// Round 4
// 478.214 us; speedup vs baseline: 2.2110x; 2.2110x over previous
//
#include <hip/hip_runtime.h>

typedef _Float16 f16;
typedef _Float16 f16x8 __attribute__((ext_vector_type(8)));
typedef float f32x4 __attribute__((ext_vector_type(4)));
typedef unsigned long long u64;
typedef unsigned u32;

// dims
#define BB 128
#define TT 128
#define IIN 512
#define HHID 512
#define EEX 256

// ---------------- prep: fp32 -> fp16 conversions + counter zeroing ----------------
__global__ void prep_kernel(const float* __restrict__ x,
    const float* __restrict__ W_ir, const float* __restrict__ W_iz, const float* __restrict__ W_in,
    const float* __restrict__ W_hr, const float* __restrict__ W_hz, const float* __restrict__ W_hn,
    f16* __restrict__ xb, f16* __restrict__ WiCat, f16* __restrict__ WhCat,
    u32* __restrict__ cnt)
{
  size_t idx = (size_t)blockIdx.x * 256 + threadIdx.x;

  const size_t NX = (size_t)TT * BB * (IIN / 8);         // 1,048,576 chunks of 8
  const size_t NW = (size_t)2 * 1536 * (512 / 8);        // 196,608 per weight set
  if (idx < NX) {
    int t = (int)(idx / (BB * 64));
    int rem = (int)(idx % (BB * 64));
    int b = rem >> 6;
    int k0 = (rem & 63) * 8;
    const float* src = x + ((size_t)b * TT + t) * IIN + k0;
    f16x8 v;
#pragma unroll
    for (int j = 0; j < 8; ++j) v[j] = (f16)src[j];
    *(f16x8*)(xb + ((size_t)t * BB + b) * IIN + k0) = v;
  } else if (idx < NX + 2 * NW) {
    size_t w = idx - NX;
    bool isI = w < NW;
    size_t w2 = isI ? w : w - NW;
    int l = (int)(w2 / (1536 * 64));
    int rem = (int)(w2 % (1536 * 64));
    int n = rem >> 6;
    int k0 = (rem & 63) * 8;
    int g = n >> 9, j = n & 511;
    const float* W = isI ? (g == 0 ? W_ir : (g == 1 ? W_iz : W_in))
                         : (g == 0 ? W_hr : (g == 1 ? W_hz : W_hn));
    const float* src = W + ((size_t)l * 512 + j) * 512 + k0;
    f16x8 v;
#pragma unroll
    for (int jj = 0; jj < 8; ++jj) v[jj] = (f16)src[jj];
    f16* dst = isI ? WiCat : WhCat;
    *(f16x8*)(dst + ((size_t)l * 1536 + n) * 512 + k0) = v;
  } else if (idx < NX + 2 * NW + 32768) {
    // zero all step counters (2 layers * 8 clusters * 128 t * 16-u32 stride)
    size_t z = idx - (NX + 2 * NW);
    __hip_atomic_store(cnt + z, 0u, __ATOMIC_RELAXED, __HIP_MEMORY_SCOPE_AGENT);
  }
}

// ---------------- er[l][b][h] = sum_e extra[b][e] * W_er[l][h][e] (f32) ----------------
__global__ void er_kernel(const float* __restrict__ extra, const float* __restrict__ W_er,
                          float* __restrict__ er)
{
  int idx = blockIdx.x * 256 + threadIdx.x;   // 2*128*512 = 131072
  int l = idx >> 16;
  int b = (idx >> 9) & 127;
  int h = idx & 511;
  const float* e = extra + (size_t)b * EEX;
  const float* w = W_er + ((size_t)l * 512 + h) * EEX;
  float acc = 0.f;
#pragma unroll 4
  for (int k = 0; k < EEX; k += 4)
    acc += e[k] * w[k] + e[k + 1] * w[k + 1] + e[k + 2] * w[k + 2] + e[k + 3] * w[k + 3];
  er[idx] = acc;
}

// ---------------- fused 2-layer recurrence ----------------
// 256 blocks x 256 threads (4 waves, 1 wave/SIMD -> 512-VGPR budget).
// block id: layer = bid>>7, cluster c = (bid>>4)&7 (16 batch rows), slice s = bid&15 (32 hid cols).
// Per wave: 48 pinned f16x8 weight B-fragments (192 VGPRs).
//   waves 0,1: Wh tiles (h @ Wh^T) ; waves 2,3: Wi tiles (inp @ Wi^T).
// Layer-0 input = xb[t] (plain loads, prefetched over barrier wait).
// Layer-1 input = h0x[t] (t-indexed coherent u32 stores by layer-0, gated by cnt0[c][t]==16).
// Intra-layer h exchange: same t-indexed coherent buffers + per-(cluster,t) counters (R2-proven).
__global__ __launch_bounds__(256, 1) void fused_recur(
    const f16* __restrict__ WiCat,   // [2][1536][512]
    const f16* __restrict__ WhCat,   // [2][1536][512]
    const f16* __restrict__ xb,      // [T*128][512]
    const float* __restrict__ er,    // [2][128][512]
    const float* __restrict__ b_ir, const float* __restrict__ b_iz, const float* __restrict__ b_in,
    float* __restrict__ outs,        // [128][T][512]
    float* __restrict__ hfin,        // [2][128][512]
    u32* __restrict__ h0x,           // [T][128][256] u32 (2 f16 each)
    u32* __restrict__ h1x,           // [T][128][256]
    u32* __restrict__ cnt)           // [2][8][128][16] u32
{
  const int tid = threadIdx.x;
  const int wave = tid >> 6, lane = tid & 63;
  const int bid = blockIdx.x;
  const int layer = bid >> 7;
  const int c = (bid >> 4) & 7;
  const int s = bid & 15;
  const int r16 = lane & 15, khi = lane >> 4;

  __shared__ f16 hL[16 * 520];        // h state, padded rows
  __shared__ f16 xL[16 * 520];        // input rows
  __shared__ float preH[6][16][17];   // h @ Wh^T partials (96 gate cols)
  __shared__ float preX[6][16][17];   // inp @ Wi^T partials
  __shared__ float hf32[16 * 32];     // fp32 master h for own slice

  // ---- pinned weight fragments ----
  const bool isWi = wave >= 2;
  const int tb = (wave & 1) * 3;      // tile base within weight-set (3 tiles/wave)
  const f16* Wsrc = (isWi ? WiCat : WhCat) + (size_t)layer * 1536 * 512;
  f16x8 wf[3][16];
#pragma unroll
  for (int ti = 0; ti < 3; ++ti) {
    int gcl = (tb + ti) * 16 + r16;   // local gate col 0..95
    int g = gcl >> 5, cig = gcl & 31;
    const f16* wr = Wsrc + (size_t)(g * 512 + s * 32 + cig) * 512 + khi * 8;
#pragma unroll
    for (int cc = 0; cc < 16; ++cc) wf[ti][cc] = *(const f16x8*)(wr + cc * 32);
  }
#pragma unroll
  for (int ti = 0; ti < 3; ++ti)
#pragma unroll
    for (int cc = 0; cc < 16; ++cc)
      asm volatile("" : "+v"(wf[ti][cc]));

  // ---- zero h state ----
  {
    f16x8 z;
#pragma unroll
    for (int j = 0; j < 8; ++j) z[j] = (f16)0.f;
    for (int i = tid; i < 16 * 520 / 8; i += 256) ((f16x8*)hL)[i] = z;
    for (int i = tid; i < 512; i += 256) hf32[i] = 0.f;
  }

  // ---- blend constants: thread owns (row, cols j0..j0+1) of the 16x32 slice ----
  const int row = tid >> 4, p = tid & 15;
  const int gr = c * 16 + row;
  const int j0 = 2 * p;
  float cbr[2], cbz[2], cbn[2];
#pragma unroll
  for (int e = 0; e < 2; ++e) {
    int jg = s * 32 + j0 + e;
    cbr[e] = b_ir[layer * 512 + jg] + er[((size_t)layer * 128 + gr) * 512 + jg];
    cbz[e] = b_iz[layer * 512 + jg];
    cbn[e] = b_in[layer * 512 + jg];
  }

  // ---- initial input (t=0) -> xL ----
  {
    u64 xr0[8];
    if (layer == 0) {
      const u64* sx = (const u64*)xb + ((size_t)0 * 128 + c * 16) * 128;
#pragma unroll
      for (int u = 0; u < 8; ++u) xr0[u] = sx[tid + u * 256];
    } else {
      if (tid == 0) {
        const u32* a = cnt + ((size_t)(0 * 8 + c) * 128 + 0) * 16;
        while (__hip_atomic_load(a, __ATOMIC_RELAXED, __HIP_MEMORY_SCOPE_AGENT) < 16u)
          __builtin_amdgcn_s_sleep(1);
      }
      __syncthreads();
      const u64* sx = (const u64*)h0x + ((size_t)0 * 128 + c * 16) * 128;
#pragma unroll
      for (int u = 0; u < 8; ++u)
        xr0[u] = __hip_atomic_load(sx + tid + u * 256, __ATOMIC_RELAXED, __HIP_MEMORY_SCOPE_AGENT);
    }
#pragma unroll
    for (int u = 0; u < 8; ++u) {
      int i = tid + u * 256, r = i >> 7, q = i & 127;
      *(u64*)(xL + r * 520 + q * 4) = xr0[u];
    }
  }
  __syncthreads();

  u32* hx_own = layer ? h1x : h0x;

  for (int t = 0; t < TT; ++t) {
    // ---- MFMA: waves 0,1 -> preH from hL; waves 2,3 -> preX from xL ----
    const f16* aL = isWi ? xL : hL;
    f32x4 ac0 = {0.f, 0.f, 0.f, 0.f}, ac1 = ac0, ac2 = ac0;
#pragma unroll
    for (int cc = 0; cc < 16; ++cc) {
      f16x8 a = *(const f16x8*)(aL + r16 * 520 + cc * 32 + khi * 8);
      ac0 = __builtin_amdgcn_mfma_f32_16x16x32_f16(a, wf[0][cc], ac0, 0, 0, 0);
      ac1 = __builtin_amdgcn_mfma_f32_16x16x32_f16(a, wf[1][cc], ac1, 0, 0, 0);
      ac2 = __builtin_amdgcn_mfma_f32_16x16x32_f16(a, wf[2][cc], ac2, 0, 0, 0);
    }
    {
      float (*pd)[16][17] = isWi ? preX : preH;
#pragma unroll
      for (int v = 0; v < 4; ++v) {
        pd[tb + 0][khi * 4 + v][r16] = ac0[v];
        pd[tb + 1][khi * 4 + v][r16] = ac1[v];
        pd[tb + 2][khi * 4 + v][r16] = ac2[v];
      }
    }
    __syncthreads();

    // ---- blend: gates + state update; publish 2 f16 as one coherent u32 ----
    float hn[2];
#pragma unroll
    for (int e = 0; e < 2; ++e) {
      int j = j0 + e;
      int jz = 32 + j, jn = 64 + j;
      float sr = preX[j >> 4][row][j & 15] + cbr[e] + preH[j >> 4][row][j & 15];
      float sz = preX[jz >> 4][row][jz & 15] + cbz[e] + preH[jz >> 4][row][jz & 15];
      float pxn = preX[jn >> 4][row][jn & 15] + cbn[e];
      float phn = preH[jn >> 4][row][jn & 15];
      float rg = 1.f / (1.f + __expf(-sr));
      float zg = 1.f / (1.f + __expf(-sz));
      float xn = pxn + rg * phn;
      xn = fminf(15.f, fmaxf(-15.f, xn));
      float e2 = __expf(2.f * xn);
      float nn = (e2 - 1.f) / (e2 + 1.f);
      int li = row * 32 + j;
      float hold = hf32[li];
      float hv = (1.f - zg) * nn + zg * hold;
      hf32[li] = hv;
      hn[e] = hv;
    }
    {
      union { f16 h2[2]; u32 u; } pk;
      pk.h2[0] = (f16)hn[0]; pk.h2[1] = (f16)hn[1];
      __hip_atomic_store(hx_own + ((size_t)t * 128 + gr) * 256 + s * 16 + p, pk.u,
                         __ATOMIC_RELAXED, __HIP_MEMORY_SCOPE_AGENT);
    }
    if (layer == 1) {
      float* o = outs + ((size_t)gr * TT + t) * 512 + s * 32 + j0;
      o[0] = hn[0]; o[1] = hn[1];
    }
    if (t == TT - 1) {
      float* hf = hfin + ((size_t)layer * 128 + gr) * 512 + s * 32 + j0;
      hf[0] = hn[0]; hf[1] = hn[1];
      if (layer == 0) {
        // publish final step for layer-1 consumers
        asm volatile("s_waitcnt vmcnt(0)" ::: "memory");
        __syncthreads();
        if (tid == 0)
          __hip_atomic_fetch_add(cnt + ((size_t)(0 * 8 + c) * 128 + t) * 16, 1u,
                                 __ATOMIC_RELAXED, __HIP_MEMORY_SCOPE_AGENT);
      }
      break;
    }

    // ---- arrive: all waves' coherent stores acked, then one atomicAdd ----
    asm volatile("s_waitcnt vmcnt(0)" ::: "memory");
    __syncthreads();
    if (tid == 0)
      __hip_atomic_fetch_add(cnt + ((size_t)(layer * 8 + c) * 128 + t) * 16, 1u,
                             __ATOMIC_RELAXED, __HIP_MEMORY_SCOPE_AGENT);

    // ---- layer-0: issue x[t+1] prefetch now (in flight across the wait) ----
    u64 xr[8];
    if (layer == 0) {
      const u64* sx = (const u64*)xb + ((size_t)(t + 1) * 128 + c * 16) * 128;
#pragma unroll
      for (int u = 0; u < 8; ++u) xr[u] = sx[tid + u * 256];
#pragma unroll
      for (int u = 0; u < 8; ++u) asm volatile("" : "+v"(xr[u]));
    }

    // ---- wait: own cluster step t complete; layer-1 also waits for h0[t+1] ----
    if (tid == 0) {
      const u32* a = cnt + ((size_t)(layer * 8 + c) * 128 + t) * 16;
      while (__hip_atomic_load(a, __ATOMIC_RELAXED, __HIP_MEMORY_SCOPE_AGENT) < 16u)
        __builtin_amdgcn_s_sleep(1);
      if (layer == 1) {
        const u32* b = cnt + ((size_t)(0 * 8 + c) * 128 + (t + 1)) * 16;
        while (__hip_atomic_load(b, __ATOMIC_RELAXED, __HIP_MEMORY_SCOPE_AGENT) < 16u)
          __builtin_amdgcn_s_sleep(1);
      }
    }
    __syncthreads();

    // ---- reload h (own layer, step t) and input (layer-1: h0[t+1]) ----
    {
      const u64* hsrc = (const u64*)hx_own + ((size_t)t * 128 + c * 16) * 128;
      u64 hv[8];
#pragma unroll
      for (int u = 0; u < 8; ++u)
        hv[u] = __hip_atomic_load(hsrc + tid + u * 256, __ATOMIC_RELAXED, __HIP_MEMORY_SCOPE_AGENT);
      u64 xv[8];
      if (layer == 1) {
        const u64* xsrc = (const u64*)h0x + ((size_t)(t + 1) * 128 + c * 16) * 128;
#pragma unroll
        for (int u = 0; u < 8; ++u)
          xv[u] = __hip_atomic_load(xsrc + tid + u * 256, __ATOMIC_RELAXED, __HIP_MEMORY_SCOPE_AGENT);
      }
#pragma unroll
      for (int u = 0; u < 8; ++u) {
        int i = tid + u * 256, r = i >> 7, q = i & 127;
        *(u64*)(hL + r * 520 + q * 4) = hv[u];
      }
      if (layer == 0) {
#pragma unroll
        for (int u = 0; u < 8; ++u) {
          int i = tid + u * 256, r = i >> 7, q = i & 127;
          *(u64*)(xL + r * 520 + q * 4) = xr[u];
        }
      } else {
#pragma unroll
        for (int u = 0; u < 8; ++u) {
          int i = tid + u * 256, r = i >> 7, q = i & 127;
          *(u64*)(xL + r * 520 + q * 4) = xv[u];
        }
      }
    }
    __syncthreads();
  }
}

// ---------------- launcher ----------------
extern "C" void kernel_launch(void* const* d_in, const int* in_sizes, int n_in,
                              void* d_out, int out_size, void* d_ws, size_t ws_size,
                              hipStream_t stream) {
  const float* x     = (const float*)d_in[0];
  const float* extra = (const float*)d_in[1];
  const float* W_ir  = (const float*)d_in[2];
  const float* b_ir  = (const float*)d_in[3];
  const float* W_hr  = (const float*)d_in[4];
  const float* W_iz  = (const float*)d_in[5];
  const float* b_iz  = (const float*)d_in[6];
  const float* W_hz  = (const float*)d_in[7];
  const float* W_in  = (const float*)d_in[8];
  const float* b_in  = (const float*)d_in[9];
  const float* W_hn  = (const float*)d_in[10];
  const float* W_er  = (const float*)d_in[11];
  float* out = (float*)d_out;

  char* ws = (char*)d_ws;
  f16* WiCat = (f16*)(ws);                    // 3,145,728 B
  f16* WhCat = (f16*)(ws + 3145728);          // 3,145,728 B
  f16* xb    = (f16*)(ws + 6291456);          // 16,777,216 B
  float* er  = (float*)(ws + 23068672);       // 524,288 B
  u32* h0x   = (u32*)(ws + 23592960);         // 16,777,216 B  [T][128][256] u32
  u32* h1x   = (u32*)(ws + 40370176);         // 16,777,216 B
  u32* cnt   = (u32*)(ws + 57147392);         // 131,072 B     [2][8][128][16] u32

  prep_kernel<<<5760, 256, 0, stream>>>(x, W_ir, W_iz, W_in, W_hr, W_hz, W_hn,
                                        xb, WiCat, WhCat, cnt);
  er_kernel<<<512, 256, 0, stream>>>(extra, W_er, er);

  float* outs = out;                              // [128][128][512]
  float* hfin = out + (size_t)BB * TT * HHID;     // [2][128][512]

  fused_recur<<<256, 256, 0, stream>>>(WiCat, WhCat, xb, er, b_ir, b_iz, b_in,
                                       outs, hfin, h0x, h1x, cnt);
}